// Round 9
// baseline (434.633 us; speedup 1.0000x reference)
//
#include <hip/hip_runtime.h>
#include <hip/hip_bf16.h>

// Kuramoto V2: B=8, N=2048, D=256, 50 steps.
//  1) normalize embeddings -> bf16 En
//  2) C = clip(En En^T, 0) -> fp8 e4m3 row-major (symmetric-store trick)
//  3) ONE persistent kernel: each block owns 64 rows of C in 128KB LDS
//     (staged once, XOR-swizzled), iterates all 50 steps.
// Sync evolution: R5 1024-spinners-one-line = 96us/step. R7 padded per-batch
// counter = 5.6us/step (32-deep RMW chain ~4.5us). R8: per-BLOCK flag words
// 128B apart -- publish = one relaxed atomic store (parallel across lines),
// wait = 32-lane parallel poll + ballot. Init tables folded in as step-0
// publish; sincos carried in registers.
// R9 = byte-identical resubmit of R8 (R8 hit the same UnresponsiveContainer
// infra error as R0's untouched stub; source was never executed).

constexpr int B = 8;
constexpr int N = 2048;
constexpr int D = 256;
constexpr int STEPS = 50;
constexpr int ROWS = 64;            // C-rows per block
constexpr int BPB  = 32;            // blocks per batch
constexpr int TPB  = 512;           // threads per block (8 waves)
constexpr float DT = 0.01f;
constexpr float K_OVER_N = 1.0f / 2048.0f;
constexpr float TWO_PI_F = 6.2831854820251465f; // float(2*pi)

using bf16x8 = __attribute__((ext_vector_type(8))) short;
using f32x4  = __attribute__((ext_vector_type(4))) float;

static __device__ __forceinline__ unsigned short f2bf(float f) {
    union { float f; unsigned int i; } v; v.f = f;
    unsigned int x = v.i;
    x += 0x7fffu + ((x >> 16) & 1u);   // RNE
    return (unsigned short)(x >> 16);
}
static __device__ __forceinline__ unsigned char f2fp8(float f) {
    return (unsigned char)(__builtin_amdgcn_cvt_pk_fp8_f32(f, f, 0, false) & 0xff);
}

// ---------------- normalize: one wave per row of 256 floats -> bf16 -------
__global__ void normalize_k(const float* __restrict__ emb,
                            unsigned short* __restrict__ En) {
    const int row  = blockIdx.x * 4 + (threadIdx.x >> 6);
    const int lane = threadIdx.x & 63;
    const float4 v = *(const float4*)(emb + (size_t)row * D + lane * 4);
    float ss = v.x * v.x + v.y * v.y + v.z * v.z + v.w * v.w;
    #pragma unroll
    for (int k = 32; k >= 1; k >>= 1) ss += __shfl_xor(ss, k);
    const float inv = 1.0f / fmaxf(sqrtf(ss), 1e-12f);
    ushort4 o;
    o.x = f2bf(v.x * inv); o.y = f2bf(v.y * inv);
    o.z = f2bf(v.z * inv); o.w = f2bf(v.w * inv);
    *(ushort4*)(En + (size_t)row * D + lane * 4) = o;
}

// ---------------- build C = clip(En En^T, 0) -> fp8 row-major --------------
// C/D frag: col = lane&15, row = (lane>>4)*4 + reg; store transposed (C sym).
__global__ __launch_bounds__(256) void build_c_k(const unsigned short* __restrict__ En,
                                                 unsigned char* __restrict__ C) {
    const int b = blockIdx.z;
    const unsigned short* Eb = En + (size_t)b * N * D;
    const int wid  = threadIdx.x >> 6;
    const int lane = threadIdx.x & 63;
    const int i_base = blockIdx.y * 64 + (wid >> 1) * 32;
    const int j_base = blockIdx.x * 64 + (wid & 1) * 32;
    const int fr = lane & 15;
    const int fk = (lane >> 4) * 8;

    f32x4 acc[2][2];
    #pragma unroll
    for (int m = 0; m < 2; ++m)
        #pragma unroll
        for (int n = 0; n < 2; ++n)
            acc[m][n] = (f32x4){0.f, 0.f, 0.f, 0.f};

    for (int k0 = 0; k0 < D; k0 += 32) {
        bf16x8 a[2], bv[2];
        #pragma unroll
        for (int m = 0; m < 2; ++m)
            a[m] = *(const bf16x8*)(Eb + (size_t)(i_base + m * 16 + fr) * D + k0 + fk);
        #pragma unroll
        for (int n = 0; n < 2; ++n)
            bv[n] = *(const bf16x8*)(Eb + (size_t)(j_base + n * 16 + fr) * D + k0 + fk);
        #pragma unroll
        for (int m = 0; m < 2; ++m)
            #pragma unroll
            for (int n = 0; n < 2; ++n)
                acc[m][n] = __builtin_amdgcn_mfma_f32_16x16x32_bf16(a[m], bv[n], acc[m][n], 0, 0, 0);
    }

    unsigned char* Cb = C + (size_t)b * N * N;
    const int orow = (lane >> 4) * 4;
    #pragma unroll
    for (int m = 0; m < 2; ++m)
        #pragma unroll
        for (int n = 0; n < 2; ++n) {
            int w = __builtin_amdgcn_cvt_pk_fp8_f32(fmaxf(acc[m][n][0], 0.f),
                                                    fmaxf(acc[m][n][1], 0.f), 0, false);
            w = __builtin_amdgcn_cvt_pk_fp8_f32(fmaxf(acc[m][n][2], 0.f),
                                                fmaxf(acc[m][n][3], 0.f), w, true);
            const int j = j_base + n * 16 + fr;
            const int i = i_base + m * 16 + orow;
            *(unsigned int*)(Cb + (size_t)j * N + i) = (unsigned int)w;
        }
}

// ---------------- persistent 50-step kernel --------------------------------
// Block = 64 rows of one batch, 8 waves: row-group grp = w>>1 (16 rows),
// K-half kh = w&1 (1024). C rows in LDS (swizzled) for all 50 steps.
// flags[b*BPB+blk] (128B apart): monotonic step stamp. init publish -> 1,
// step-s publish -> s+2. Step s waits all 32 flags >= s+1.
__global__ __launch_bounds__(512, 2) void fused_steps_k(
        const unsigned char* __restrict__ C,
        unsigned char* __restrict__ tbl0,
        unsigned char* __restrict__ tbl1,
        const float* __restrict__ theta0,
        float* __restrict__ out,
        const float* __restrict__ omega,
        unsigned int* __restrict__ flags) {
    __shared__ unsigned char s_C[ROWS * 2048];     // 128 KB, swizzled
    __shared__ unsigned char s_tbl[2080 + 2048];   // cos | pad32 | sin
    __shared__ f32x4 s_acc[8][8];                  // [wave][g*2+col]

    const int rt = blockIdx.x;        // 0..31: rows rt*64..rt*64+63
    const int b  = blockIdx.y;
    const int t  = threadIdx.x;
    const int w = t >> 6, lane = t & 63;
    const int col = lane & 15, g = lane >> 4;
    const int grp = w >> 1, kh = w & 1;

    // ---- per-row register state (t < 64) + init-table publish (flag=1) ----
    float th = 0.f, sth = 0.f, cth = 0.f, om = 0.f;
    if (t < ROWS) {
        th = theta0[(size_t)b * N + rt * ROWS + t];
        om = omega[rt * ROWS + t];
        sincosf(th, &sth, &cth);
        tbl0[(size_t)b * 4096 + rt * ROWS + t] = f2fp8(cth);
        tbl0[(size_t)b * 4096 + 2048 + rt * ROWS + t] = f2fp8(sth);
    }
    if (t == 0) {
        __builtin_amdgcn_fence(__ATOMIC_RELEASE, "agent");
        __hip_atomic_store(&flags[((size_t)b * BPB + rt) * 32], 1u,
                           __ATOMIC_RELAXED, __HIP_MEMORY_SCOPE_AGENT);
    }

    // ---- stage my 64 C-rows into LDS once, XOR-swizzle 16B units ----
    {
        const unsigned char* src = C + ((size_t)b * N + rt * ROWS) * N;
        #pragma unroll
        for (int it = 0; it < 16; ++it) {
            const int idx = it * TPB + t;        // 16B-unit index, 0..8191
            const int row = idx >> 7;            // 128 units per 2048B row
            const int o   = (idx & 127) * 16;
            const uint4 v = *(const uint4*)(src + (size_t)row * N + o);
            *(uint4*)(s_C + row * 2048 + (o ^ ((row & 7) << 4))) = v;
        }
    }

    const unsigned char* Abase = s_C + (grp * 16 + col) * 2048;
    const unsigned int sw = (unsigned)((col & 7) << 4);
    const int tblbase = (col == 1) ? 2080 : 0;    // col1 -> sin; else cos
    const int o0 = kh * 1024 + g * 8;
    const unsigned int* pollp = &flags[((size_t)b * BPB + (lane & 31)) * 32];
    unsigned int* myflag = &flags[((size_t)b * BPB + rt) * 32];

    for (int s = 0; s < STEPS; ++s) {
        // ---- wait for all 32 producers of this step's input tables ----
        if (w == 0) {
            const unsigned int tgt = (unsigned int)(s + 1);
            for (;;) {
                const unsigned int v = __hip_atomic_load(pollp, __ATOMIC_RELAXED,
                                                         __HIP_MEMORY_SCOPE_AGENT);
                if (__ballot(v >= tgt) == ~0ull) break;
                __builtin_amdgcn_s_sleep(4);
            }
            __builtin_amdgcn_fence(__ATOMIC_ACQUIRE, "agent");
        }
        __syncthreads();

        // ---- stage this step's tables (4 KB) ----
        const unsigned char* tI = ((s & 1) ? tbl1 : tbl0) + (size_t)b * 4096;
        if (t < 128)
            *(uint4*)(s_tbl + t * 16) = *(const uint4*)(tI + t * 16);
        else if (t < 256) {
            const int u = t - 128;
            *(uint4*)(s_tbl + 2080 + u * 16) = *(const uint4*)(tI + 2048 + u * 16);
        }
        __syncthreads();

        // ---- dual matvec via fp8 MFMA, A from swizzled LDS, 2-acc ILP ----
        f32x4 acc0 = {0.f, 0.f, 0.f, 0.f}, acc1 = {0.f, 0.f, 0.f, 0.f};
        #pragma unroll
        for (int u = 0; u < 32; u += 2) {
            const int oa = o0 + u * 32;
            const long a0 = *(const long*)(Abase + (oa ^ sw));
            const long a1 = *(const long*)(Abase + ((oa + 32) ^ sw));
            long b0 = *(const long*)(s_tbl + tblbase + oa);
            long b1 = *(const long*)(s_tbl + tblbase + oa + 32);
            b0 = (col < 2) ? b0 : 0L;
            b1 = (col < 2) ? b1 : 0L;
            acc0 = __builtin_amdgcn_mfma_f32_16x16x32_fp8_fp8(a0, b0, acc0, 0, 0, 0);
            acc1 = __builtin_amdgcn_mfma_f32_16x16x32_fp8_fp8(a1, b1, acc1, 0, 0, 0);
        }
        acc0 += acc1;
        if (col < 2) s_acc[w][g * 2 + col] = acc0;
        __syncthreads();

        // ---- finalize rows (64 writers, all in wave 0) ----
        if (t < ROWS) {
            const int gr = t >> 4;                   // row-group
            const int gg = ((t & 15) >> 2) * 2;      // s_acc slot base
            const int rr = t & 3;                    // reg within frag
            float S1 = 0.f, S2 = 0.f;
            #pragma unroll
            for (int h = 0; h < 2; ++h) {            // two K-halves
                S1 += s_acc[gr * 2 + h][gg + 0][rr];
                S2 += s_acc[gr * 2 + h][gg + 1][rr];
            }
            const float csum = sth * S1 - cth * S2;
            th = fmodf(th + DT * (om + K_OVER_N * csum), TWO_PI_F);
            if (s == STEPS - 1) {
                out[(size_t)b * N + rt * ROWS + t] = th;
            } else {
                sincosf(th, &sth, &cth);
                unsigned char* tO = (((s + 1) & 1) ? tbl1 : tbl0) + (size_t)b * 4096;
                tO[rt * ROWS + t] = f2fp8(cth);
                tO[2048 + rt * ROWS + t] = f2fp8(sth);
            }
        }
        // ---- publish (writers all in wave 0; lane 0's fence covers wave) --
        if (s < STEPS - 1 && t == 0) {
            __builtin_amdgcn_fence(__ATOMIC_RELEASE, "agent");
            __hip_atomic_store(myflag, (unsigned int)(s + 2),
                               __ATOMIC_RELAXED, __HIP_MEMORY_SCOPE_AGENT);
        }
    }
}

extern "C" void kernel_launch(void* const* d_in, const int* in_sizes, int n_in,
                              void* d_out, int out_size, void* d_ws, size_t ws_size,
                              hipStream_t stream) {
    const float* theta0 = (const float*)d_in[0];  // [B,N]
    const float* emb    = (const float*)d_in[1];  // [B,N,D]
    const float* omega  = (const float*)d_in[2];  // [N]
    float* out = (float*)d_out;                   // [B,N]

    // workspace layout (~42 MiB)
    unsigned short* En = (unsigned short*)d_ws;                    // B*N*D bf16
    unsigned char*  C  = (unsigned char*)(En + (size_t)B * N * D); // B*N*N fp8
    unsigned char* tb0 = C + (size_t)B * N * N;                    // B*4096 fp8
    unsigned char* tb1 = tb0 + (size_t)B * 4096;                   // B*4096 fp8
    unsigned int* flags = (unsigned int*)(tb1 + (size_t)B * 4096); // B*32 x 128B

    (void)hipMemsetAsync(flags, 0, B * BPB * 32 * sizeof(unsigned int), stream);

    normalize_k<<<B * N / 4, 256, 0, stream>>>(emb, En);

    dim3 gC(N / 64, N / 64, B);
    build_c_k<<<gC, 256, 0, stream>>>(En, C);

    fused_steps_k<<<dim3(BPB, B), TPB, 0, stream>>>(C, tb0, tb1, theta0,
                                                    out, omega, flags);
}

// Round 10
// 265.224 us; speedup vs baseline: 1.6387x; 1.6387x over previous
//
#include <hip/hip_runtime.h>
#include <hip/hip_bf16.h>

// Kuramoto V2: B=8, N=2048, D=256, 50 steps.
//  1) normalize embeddings -> bf16 En
//  2) C = clip(En En^T, 0) -> fp8 e4m3 row-major (symmetric-store trick)
//  3) ONE persistent kernel: each block owns 64 rows of C in 128KB LDS
//     (staged once, XOR-swizzled), iterates all 50 steps.
// Sync evolution: R5 1024-spinners-one-line = 96us/step. R7 per-batch counter
// = 5.6us/step. R9 per-block flags+fences = 6.1us/step (A/B: RMW chain was
// NOT the cost; the fences + separate table fetch were). R10: DATA AS THE
// MESSAGE -- one u32 per row = stamp<<16 | sin_fp8<<8 | cos_fp8, relaxed
// agent-scope atomics, parity double-buffer, exact stamp match. No fences,
// no flags, no separate table read: one LLC store + one LLC poll per step.

constexpr int B = 8;
constexpr int N = 2048;
constexpr int D = 256;
constexpr int STEPS = 50;
constexpr int ROWS = 64;            // C-rows per block
constexpr int BPB  = 32;            // blocks per batch
constexpr int TPB  = 512;           // threads per block (8 waves)
constexpr float DT = 0.01f;
constexpr float K_OVER_N = 1.0f / 2048.0f;
constexpr float TWO_PI_F = 6.2831854820251465f; // float(2*pi)

using bf16x8 = __attribute__((ext_vector_type(8))) short;
using f32x4  = __attribute__((ext_vector_type(4))) float;

static __device__ __forceinline__ unsigned short f2bf(float f) {
    union { float f; unsigned int i; } v; v.f = f;
    unsigned int x = v.i;
    x += 0x7fffu + ((x >> 16) & 1u);   // RNE
    return (unsigned short)(x >> 16);
}
static __device__ __forceinline__ unsigned char f2fp8(float f) {
    return (unsigned char)(__builtin_amdgcn_cvt_pk_fp8_f32(f, f, 0, false) & 0xff);
}

// ---------------- normalize: one wave per row of 256 floats -> bf16 -------
__global__ void normalize_k(const float* __restrict__ emb,
                            unsigned short* __restrict__ En) {
    const int row  = blockIdx.x * 4 + (threadIdx.x >> 6);
    const int lane = threadIdx.x & 63;
    const float4 v = *(const float4*)(emb + (size_t)row * D + lane * 4);
    float ss = v.x * v.x + v.y * v.y + v.z * v.z + v.w * v.w;
    #pragma unroll
    for (int k = 32; k >= 1; k >>= 1) ss += __shfl_xor(ss, k);
    const float inv = 1.0f / fmaxf(sqrtf(ss), 1e-12f);
    ushort4 o;
    o.x = f2bf(v.x * inv); o.y = f2bf(v.y * inv);
    o.z = f2bf(v.z * inv); o.w = f2bf(v.w * inv);
    *(ushort4*)(En + (size_t)row * D + lane * 4) = o;
}

// ---------------- build C = clip(En En^T, 0) -> fp8 row-major --------------
// C/D frag: col = lane&15, row = (lane>>4)*4 + reg; store transposed (C sym).
__global__ __launch_bounds__(256) void build_c_k(const unsigned short* __restrict__ En,
                                                 unsigned char* __restrict__ C) {
    const int b = blockIdx.z;
    const unsigned short* Eb = En + (size_t)b * N * D;
    const int wid  = threadIdx.x >> 6;
    const int lane = threadIdx.x & 63;
    const int i_base = blockIdx.y * 64 + (wid >> 1) * 32;
    const int j_base = blockIdx.x * 64 + (wid & 1) * 32;
    const int fr = lane & 15;
    const int fk = (lane >> 4) * 8;

    f32x4 acc[2][2];
    #pragma unroll
    for (int m = 0; m < 2; ++m)
        #pragma unroll
        for (int n = 0; n < 2; ++n)
            acc[m][n] = (f32x4){0.f, 0.f, 0.f, 0.f};

    for (int k0 = 0; k0 < D; k0 += 32) {
        bf16x8 a[2], bv[2];
        #pragma unroll
        for (int m = 0; m < 2; ++m)
            a[m] = *(const bf16x8*)(Eb + (size_t)(i_base + m * 16 + fr) * D + k0 + fk);
        #pragma unroll
        for (int n = 0; n < 2; ++n)
            bv[n] = *(const bf16x8*)(Eb + (size_t)(j_base + n * 16 + fr) * D + k0 + fk);
        #pragma unroll
        for (int m = 0; m < 2; ++m)
            #pragma unroll
            for (int n = 0; n < 2; ++n)
                acc[m][n] = __builtin_amdgcn_mfma_f32_16x16x32_bf16(a[m], bv[n], acc[m][n], 0, 0, 0);
    }

    unsigned char* Cb = C + (size_t)b * N * N;
    const int orow = (lane >> 4) * 4;
    #pragma unroll
    for (int m = 0; m < 2; ++m)
        #pragma unroll
        for (int n = 0; n < 2; ++n) {
            int w = __builtin_amdgcn_cvt_pk_fp8_f32(fmaxf(acc[m][n][0], 0.f),
                                                    fmaxf(acc[m][n][1], 0.f), 0, false);
            w = __builtin_amdgcn_cvt_pk_fp8_f32(fmaxf(acc[m][n][2], 0.f),
                                                fmaxf(acc[m][n][3], 0.f), w, true);
            const int j = j_base + n * 16 + fr;
            const int i = i_base + m * 16 + orow;
            *(unsigned int*)(Cb + (size_t)j * N + i) = (unsigned int)w;
        }
}

// ---------------- persistent 50-step kernel --------------------------------
// Block = 64 rows of one batch, 8 waves: row-group grp = w>>1 (16 rows),
// K-half kh = w&1 (1024). C rows in LDS (swizzled) for all 50 steps.
// Messages: msg[parity][b][row] u32 = stamp<<16 | sin_fp8<<8 | cos_fp8.
// Step s consumes msg[s&1] with stamp==s+1; publishes msg[(s+1)&1] stamp s+2.
// Init publish = stamp 1 into msg[0]. Exact match + parity buffer + block
// barriers make producer-lap and replay-stale cases impossible.
__global__ __launch_bounds__(512, 2) void fused_steps_k(
        const unsigned char* __restrict__ C,
        const float* __restrict__ theta0,
        float* __restrict__ out,
        const float* __restrict__ omega,
        unsigned int* __restrict__ msg) {
    __shared__ unsigned char s_C[ROWS * 2048];     // 128 KB, swizzled
    __shared__ unsigned char s_tbl[2080 + 2048];   // cos | pad32 | sin
    __shared__ f32x4 s_acc[8][8];                  // [wave][g*2+col]

    const int rt = blockIdx.x;        // 0..31: rows rt*64..rt*64+63
    const int b  = blockIdx.y;
    const int t  = threadIdx.x;
    const int w = t >> 6, lane = t & 63;
    const int col = lane & 15, g = lane >> 4;
    const int grp = w >> 1, kh = w & 1;

    // ---- per-row register state (t < 64) + init publish (stamp 1) ----
    float th = 0.f, sth = 0.f, cth = 0.f, om = 0.f;
    if (t < ROWS) {
        th = theta0[(size_t)b * N + rt * ROWS + t];
        om = omega[rt * ROWS + t];
        sincosf(th, &sth, &cth);
        const unsigned int m = (1u << 16) |
            ((unsigned int)f2fp8(sth) << 8) | (unsigned int)f2fp8(cth);
        __hip_atomic_store(&msg[(size_t)b * N + rt * ROWS + t], m,
                           __ATOMIC_RELAXED, __HIP_MEMORY_SCOPE_AGENT);
    }

    // ---- stage my 64 C-rows into LDS once, XOR-swizzle 16B units ----
    {
        const unsigned char* src = C + ((size_t)b * N + rt * ROWS) * N;
        #pragma unroll
        for (int it = 0; it < 16; ++it) {
            const int idx = it * TPB + t;        // 16B-unit index, 0..8191
            const int row = idx >> 7;            // 128 units per 2048B row
            const int o   = (idx & 127) * 16;
            const uint4 v = *(const uint4*)(src + (size_t)row * N + o);
            *(uint4*)(s_C + row * 2048 + (o ^ ((row & 7) << 4))) = v;
        }
    }

    const unsigned char* Abase = s_C + (grp * 16 + col) * 2048;
    const unsigned int sw = (unsigned)((col & 7) << 4);
    const int tblbase = (col == 1) ? 2080 : 0;    // col1 -> sin; else cos
    const int o0 = kh * 1024 + g * 8;
    const int r0 = t * 4;                         // 4 rows polled per thread

    for (int s = 0; s < STEPS; ++s) {
        // ---- consume: poll 4 payload dwords until stamp == s+1 ----
        const unsigned int* mb = msg + ((size_t)(s & 1) * B + b) * N + r0;
        const unsigned int tgt = (unsigned int)(s + 1);
        unsigned int g0, g1, g2, g3;
        for (;;) {
            g0 = __hip_atomic_load(mb + 0, __ATOMIC_RELAXED, __HIP_MEMORY_SCOPE_AGENT);
            g1 = __hip_atomic_load(mb + 1, __ATOMIC_RELAXED, __HIP_MEMORY_SCOPE_AGENT);
            g2 = __hip_atomic_load(mb + 2, __ATOMIC_RELAXED, __HIP_MEMORY_SCOPE_AGENT);
            g3 = __hip_atomic_load(mb + 3, __ATOMIC_RELAXED, __HIP_MEMORY_SCOPE_AGENT);
            if (((g0 >> 16) == tgt) & ((g1 >> 16) == tgt) &
                ((g2 >> 16) == tgt) & ((g3 >> 16) == tgt)) break;
            __builtin_amdgcn_s_sleep(2);
        }
        // unpack payload straight into LDS tables (4 cos + 4 sin bytes)
        const unsigned int uc = (g0 & 0xffu) | ((g1 & 0xffu) << 8) |
                                ((g2 & 0xffu) << 16) | ((g3 & 0xffu) << 24);
        const unsigned int us = ((g0 >> 8) & 0xffu) | (((g1 >> 8) & 0xffu) << 8) |
                                (((g2 >> 8) & 0xffu) << 16) | (((g3 >> 8) & 0xffu) << 24);
        *(unsigned int*)(s_tbl + r0) = uc;
        *(unsigned int*)(s_tbl + 2080 + r0) = us;
        __syncthreads();

        // ---- dual matvec via fp8 MFMA, A from swizzled LDS, 2-acc ILP ----
        f32x4 acc0 = {0.f, 0.f, 0.f, 0.f}, acc1 = {0.f, 0.f, 0.f, 0.f};
        #pragma unroll
        for (int u = 0; u < 32; u += 2) {
            const int oa = o0 + u * 32;
            const long a0 = *(const long*)(Abase + (oa ^ sw));
            const long a1 = *(const long*)(Abase + ((oa + 32) ^ sw));
            long b0 = *(const long*)(s_tbl + tblbase + oa);
            long b1 = *(const long*)(s_tbl + tblbase + oa + 32);
            b0 = (col < 2) ? b0 : 0L;
            b1 = (col < 2) ? b1 : 0L;
            acc0 = __builtin_amdgcn_mfma_f32_16x16x32_fp8_fp8(a0, b0, acc0, 0, 0, 0);
            acc1 = __builtin_amdgcn_mfma_f32_16x16x32_fp8_fp8(a1, b1, acc1, 0, 0, 0);
        }
        acc0 += acc1;
        if (col < 2) s_acc[w][g * 2 + col] = acc0;
        __syncthreads();

        // ---- finalize rows (64 writers, all in wave 0) + publish ----
        if (t < ROWS) {
            const int gr = t >> 4;                   // row-group
            const int gg = ((t & 15) >> 2) * 2;      // s_acc slot base
            const int rr = t & 3;                    // reg within frag
            float S1 = 0.f, S2 = 0.f;
            #pragma unroll
            for (int h = 0; h < 2; ++h) {            // two K-halves
                S1 += s_acc[gr * 2 + h][gg + 0][rr];
                S2 += s_acc[gr * 2 + h][gg + 1][rr];
            }
            const float csum = sth * S1 - cth * S2;
            th = fmodf(th + DT * (om + K_OVER_N * csum), TWO_PI_F);
            if (s == STEPS - 1) {
                out[(size_t)b * N + rt * ROWS + t] = th;
            } else {
                sincosf(th, &sth, &cth);
                const unsigned int m = ((unsigned int)(s + 2) << 16) |
                    ((unsigned int)f2fp8(sth) << 8) | (unsigned int)f2fp8(cth);
                __hip_atomic_store(
                    &msg[((size_t)((s + 1) & 1) * B + b) * N + rt * ROWS + t],
                    m, __ATOMIC_RELAXED, __HIP_MEMORY_SCOPE_AGENT);
            }
        }
    }
}

extern "C" void kernel_launch(void* const* d_in, const int* in_sizes, int n_in,
                              void* d_out, int out_size, void* d_ws, size_t ws_size,
                              hipStream_t stream) {
    const float* theta0 = (const float*)d_in[0];  // [B,N]
    const float* emb    = (const float*)d_in[1];  // [B,N,D]
    const float* omega  = (const float*)d_in[2];  // [N]
    float* out = (float*)d_out;                   // [B,N]

    // workspace layout (~42 MiB)
    unsigned short* En = (unsigned short*)d_ws;                    // B*N*D bf16
    unsigned char*  C  = (unsigned char*)(En + (size_t)B * N * D); // B*N*N fp8
    unsigned int*  msg = (unsigned int*)(C + (size_t)B * N * N);   // 2*B*N u32

    normalize_k<<<B * N / 4, 256, 0, stream>>>(emb, En);

    dim3 gC(N / 64, N / 64, B);
    build_c_k<<<gC, 256, 0, stream>>>(En, C);

    fused_steps_k<<<dim3(BPB, B), TPB, 0, stream>>>(C, theta0, out, omega, msg);
}

// Round 11
// 189.831 us; speedup vs baseline: 2.2896x; 1.3972x over previous
//
#include <hip/hip_runtime.h>
#include <hip/hip_bf16.h>

// Kuramoto V2: B=8, N=2048, D=256, 50 steps.
//  1) normalize embeddings -> bf16 En
//  2) C = clip(En En^T, 0) -> fp8 e4m3 row-major (symmetric-store trick).
//     R11: panels LDS-staged (XOR-swizzled) -- R10 build was latency-bound
//     on direct global frag loads (MfmaUtil 8.7%, Occ 28%).
//  3) ONE persistent kernel: each block owns 64 rows of C in 128KB LDS
//     (staged once, XOR-swizzled), iterates all 50 steps.
// Sync: R10 "data as the message": msg u32 = stamp<<16|sin8<<8|cos8, relaxed
// agent atomics, parity dbuf, exact stamp match (2.8us/step, no fences).
// R11 micros: __sinf/__cosf on publish path, fmod -> exact Sterbenz subtract,
// publish before out-store, s_sleep(1).

constexpr int B = 8;
constexpr int N = 2048;
constexpr int D = 256;
constexpr int STEPS = 50;
constexpr int ROWS = 64;            // C-rows per block (fused)
constexpr int BPB  = 32;            // blocks per batch (fused)
constexpr int TPB  = 512;           // threads per block (fused)
constexpr float DT = 0.01f;
constexpr float K_OVER_N = 1.0f / 2048.0f;
constexpr float TWO_PI_F = 6.2831854820251465f; // float(2*pi)

using bf16x8 = __attribute__((ext_vector_type(8))) short;
using f32x4  = __attribute__((ext_vector_type(4))) float;

static __device__ __forceinline__ unsigned short f2bf(float f) {
    union { float f; unsigned int i; } v; v.f = f;
    unsigned int x = v.i;
    x += 0x7fffu + ((x >> 16) & 1u);   // RNE
    return (unsigned short)(x >> 16);
}
static __device__ __forceinline__ unsigned char f2fp8(float f) {
    return (unsigned char)(__builtin_amdgcn_cvt_pk_fp8_f32(f, f, 0, false) & 0xff);
}

// ---------------- normalize: one wave per row of 256 floats -> bf16 -------
__global__ void normalize_k(const float* __restrict__ emb,
                            unsigned short* __restrict__ En) {
    const int row  = blockIdx.x * 4 + (threadIdx.x >> 6);
    const int lane = threadIdx.x & 63;
    const float4 v = *(const float4*)(emb + (size_t)row * D + lane * 4);
    float ss = v.x * v.x + v.y * v.y + v.z * v.z + v.w * v.w;
    #pragma unroll
    for (int k = 32; k >= 1; k >>= 1) ss += __shfl_xor(ss, k);
    const float inv = 1.0f / fmaxf(sqrtf(ss), 1e-12f);
    ushort4 o;
    o.x = f2bf(v.x * inv); o.y = f2bf(v.y * inv);
    o.z = f2bf(v.z * inv); o.w = f2bf(v.w * inv);
    *(ushort4*)(En + (size_t)row * D + lane * 4) = o;
}

// ---------------- build C = clip(En En^T, 0) -> fp8 row-major --------------
// 64x64 tile, 4 waves of 32x32. Panels staged in LDS (32KB each) with
// 16B-unit XOR swizzle (unit ^ (row&7)); K-loop entirely from ds_read_b128.
// C/D frag: col = lane&15, row = (lane>>4)*4 + reg; store transposed (C sym).
__global__ __launch_bounds__(256) void build_c_k(const unsigned short* __restrict__ En,
                                                 unsigned char* __restrict__ C) {
    __shared__ unsigned char s_Ai[64 * 512];   // 32 KB, swizzled
    __shared__ unsigned char s_Aj[64 * 512];   // 32 KB, swizzled
    const int b  = blockIdx.z;
    const int ti = blockIdx.y, tj = blockIdx.x;
    const unsigned short* Eb = En + (size_t)b * N * D;
    const int t = threadIdx.x;
    const int wid  = t >> 6;
    const int lane = t & 63;

    // ---- stage both panels (reg-staged, coalesced reads, swizzled writes) --
    {
        const unsigned char* srcI = (const unsigned char*)(Eb + (size_t)ti * 64 * D);
        const unsigned char* srcJ = (const unsigned char*)(Eb + (size_t)tj * 64 * D);
        #pragma unroll
        for (int it = 0; it < 8; ++it) {
            const int L   = it * 256 + t;       // 16B-unit index, 0..2047
            const int row = L >> 5;             // 32 units (512B) per row
            const int u   = L & 31;
            const int doff = row * 512 + ((u * 16) ^ ((row & 7) << 4));
            const int goff = row * 512 + u * 16;
            *(uint4*)(s_Ai + doff) = *(const uint4*)(srcI + goff);
            *(uint4*)(s_Aj + doff) = *(const uint4*)(srcJ + goff);
        }
    }
    __syncthreads();

    const int i_off = (wid >> 1) * 32;
    const int j_off = (wid & 1) * 32;
    const int fr = lane & 15;
    const int fq = lane >> 4;                   // k-subgroup (8 elem = 16 B)

    f32x4 acc[2][2];
    #pragma unroll
    for (int m = 0; m < 2; ++m)
        #pragma unroll
        for (int n = 0; n < 2; ++n)
            acc[m][n] = (f32x4){0.f, 0.f, 0.f, 0.f};

    #pragma unroll
    for (int k0 = 0; k0 < 512; k0 += 64) {      // 64 B = 32 elements per step
        bf16x8 a[2], bv[2];
        #pragma unroll
        for (int m = 0; m < 2; ++m) {
            const int row = i_off + m * 16 + fr;
            a[m] = *(const bf16x8*)(s_Ai + row * 512 + ((k0 + fq * 16) ^ ((row & 7) << 4)));
        }
        #pragma unroll
        for (int n = 0; n < 2; ++n) {
            const int row = j_off + n * 16 + fr;
            bv[n] = *(const bf16x8*)(s_Aj + row * 512 + ((k0 + fq * 16) ^ ((row & 7) << 4)));
        }
        #pragma unroll
        for (int m = 0; m < 2; ++m)
            #pragma unroll
            for (int n = 0; n < 2; ++n)
                acc[m][n] = __builtin_amdgcn_mfma_f32_16x16x32_bf16(a[m], bv[n], acc[m][n], 0, 0, 0);
    }

    unsigned char* Cb = C + (size_t)b * N * N;
    const int i_base = ti * 64 + i_off;
    const int j_base = tj * 64 + j_off;
    const int orow = fq * 4;
    #pragma unroll
    for (int m = 0; m < 2; ++m)
        #pragma unroll
        for (int n = 0; n < 2; ++n) {
            int w = __builtin_amdgcn_cvt_pk_fp8_f32(fmaxf(acc[m][n][0], 0.f),
                                                    fmaxf(acc[m][n][1], 0.f), 0, false);
            w = __builtin_amdgcn_cvt_pk_fp8_f32(fmaxf(acc[m][n][2], 0.f),
                                                fmaxf(acc[m][n][3], 0.f), w, true);
            const int j = j_base + n * 16 + fr;
            const int i = i_base + m * 16 + orow;
            *(unsigned int*)(Cb + (size_t)j * N + i) = (unsigned int)w;
        }
}

// ---------------- persistent 50-step kernel --------------------------------
// Block = 64 rows of one batch, 8 waves: row-group grp = w>>1 (16 rows),
// K-half kh = w&1 (1024). C rows in LDS (swizzled) for all 50 steps.
// Messages: msg[parity][b][row] u32 = stamp<<16 | sin_fp8<<8 | cos_fp8.
// Step s consumes msg[s&1] with stamp==s+1; publishes msg[(s+1)&1] stamp s+2.
__global__ __launch_bounds__(512, 2) void fused_steps_k(
        const unsigned char* __restrict__ C,
        const float* __restrict__ theta0,
        float* __restrict__ out,
        const float* __restrict__ omega,
        unsigned int* __restrict__ msg) {
    __shared__ unsigned char s_C[ROWS * 2048];     // 128 KB, swizzled
    __shared__ unsigned char s_tbl[2080 + 2048];   // cos | pad32 | sin
    __shared__ f32x4 s_acc[8][8];                  // [wave][g*2+col]

    const int rt = blockIdx.x;        // 0..31: rows rt*64..rt*64+63
    const int b  = blockIdx.y;
    const int t  = threadIdx.x;
    const int w = t >> 6, lane = t & 63;
    const int col = lane & 15, g = lane >> 4;
    const int grp = w >> 1, kh = w & 1;

    // ---- per-row register state (t < 64) + init publish (stamp 1) ----
    float th = 0.f, sth = 0.f, cth = 0.f, om = 0.f;
    if (t < ROWS) {
        th = theta0[(size_t)b * N + rt * ROWS + t];
        om = omega[rt * ROWS + t];
        sth = __sinf(th); cth = __cosf(th);
        const unsigned int m = (1u << 16) |
            ((unsigned int)f2fp8(sth) << 8) | (unsigned int)f2fp8(cth);
        __hip_atomic_store(&msg[(size_t)b * N + rt * ROWS + t], m,
                           __ATOMIC_RELAXED, __HIP_MEMORY_SCOPE_AGENT);
    }

    // ---- stage my 64 C-rows into LDS once, XOR-swizzle 16B units ----
    {
        const unsigned char* src = C + ((size_t)b * N + rt * ROWS) * N;
        #pragma unroll
        for (int it = 0; it < 16; ++it) {
            const int idx = it * TPB + t;        // 16B-unit index, 0..8191
            const int row = idx >> 7;            // 128 units per 2048B row
            const int o   = (idx & 127) * 16;
            const uint4 v = *(const uint4*)(src + (size_t)row * N + o);
            *(uint4*)(s_C + row * 2048 + (o ^ ((row & 7) << 4))) = v;
        }
    }

    const unsigned char* Abase = s_C + (grp * 16 + col) * 2048;
    const unsigned int sw = (unsigned)((col & 7) << 4);
    const int tblbase = (col == 1) ? 2080 : 0;    // col1 -> sin; else cos
    const int o0 = kh * 1024 + g * 8;
    const int r0 = t * 4;                         // 4 rows polled per thread

    for (int s = 0; s < STEPS; ++s) {
        // ---- consume: poll 4 payload dwords until stamp == s+1 ----
        const unsigned int* mb = msg + ((size_t)(s & 1) * B + b) * N + r0;
        const unsigned int tgt = (unsigned int)(s + 1);
        unsigned int g0, g1, g2, g3;
        for (;;) {
            g0 = __hip_atomic_load(mb + 0, __ATOMIC_RELAXED, __HIP_MEMORY_SCOPE_AGENT);
            g1 = __hip_atomic_load(mb + 1, __ATOMIC_RELAXED, __HIP_MEMORY_SCOPE_AGENT);
            g2 = __hip_atomic_load(mb + 2, __ATOMIC_RELAXED, __HIP_MEMORY_SCOPE_AGENT);
            g3 = __hip_atomic_load(mb + 3, __ATOMIC_RELAXED, __HIP_MEMORY_SCOPE_AGENT);
            if (((g0 >> 16) == tgt) & ((g1 >> 16) == tgt) &
                ((g2 >> 16) == tgt) & ((g3 >> 16) == tgt)) break;
            __builtin_amdgcn_s_sleep(1);
        }
        // unpack payload straight into LDS tables (4 cos + 4 sin bytes)
        const unsigned int uc = (g0 & 0xffu) | ((g1 & 0xffu) << 8) |
                                ((g2 & 0xffu) << 16) | ((g3 & 0xffu) << 24);
        const unsigned int us = ((g0 >> 8) & 0xffu) | (((g1 >> 8) & 0xffu) << 8) |
                                (((g2 >> 8) & 0xffu) << 16) | (((g3 >> 8) & 0xffu) << 24);
        *(unsigned int*)(s_tbl + r0) = uc;
        *(unsigned int*)(s_tbl + 2080 + r0) = us;
        __syncthreads();

        // ---- dual matvec via fp8 MFMA, A from swizzled LDS, 2-acc ILP ----
        f32x4 acc0 = {0.f, 0.f, 0.f, 0.f}, acc1 = {0.f, 0.f, 0.f, 0.f};
        #pragma unroll
        for (int u = 0; u < 32; u += 2) {
            const int oa = o0 + u * 32;
            const long a0 = *(const long*)(Abase + (oa ^ sw));
            const long a1 = *(const long*)(Abase + ((oa + 32) ^ sw));
            long b0 = *(const long*)(s_tbl + tblbase + oa);
            long b1 = *(const long*)(s_tbl + tblbase + oa + 32);
            b0 = (col < 2) ? b0 : 0L;
            b1 = (col < 2) ? b1 : 0L;
            acc0 = __builtin_amdgcn_mfma_f32_16x16x32_fp8_fp8(a0, b0, acc0, 0, 0, 0);
            acc1 = __builtin_amdgcn_mfma_f32_16x16x32_fp8_fp8(a1, b1, acc1, 0, 0, 0);
        }
        acc0 += acc1;
        if (col < 2) s_acc[w][g * 2 + col] = acc0;
        __syncthreads();

        // ---- finalize rows (64 writers, all in wave 0): publish FIRST ----
        if (t < ROWS) {
            const int gr = t >> 4;                   // row-group
            const int gg = ((t & 15) >> 2) * 2;      // s_acc slot base
            const int rr = t & 3;                    // reg within frag
            float S1 = 0.f, S2 = 0.f;
            #pragma unroll
            for (int h = 0; h < 2; ++h) {            // two K-halves
                S1 += s_acc[gr * 2 + h][gg + 0][rr];
                S2 += s_acc[gr * 2 + h][gg + 1][rr];
            }
            const float csum = sth * S1 - cth * S2;
            th = th + DT * (om + K_OVER_N * csum);
            if (th >= TWO_PI_F) th -= TWO_PI_F;      // exact (Sterbenz) == fmodf
            if (s < STEPS - 1) {
                sth = __sinf(th); cth = __cosf(th);
                const unsigned int m = ((unsigned int)(s + 2) << 16) |
                    ((unsigned int)f2fp8(sth) << 8) | (unsigned int)f2fp8(cth);
                __hip_atomic_store(
                    &msg[((size_t)((s + 1) & 1) * B + b) * N + rt * ROWS + t],
                    m, __ATOMIC_RELAXED, __HIP_MEMORY_SCOPE_AGENT);
            } else {
                out[(size_t)b * N + rt * ROWS + t] = th;
            }
        }
    }
}

extern "C" void kernel_launch(void* const* d_in, const int* in_sizes, int n_in,
                              void* d_out, int out_size, void* d_ws, size_t ws_size,
                              hipStream_t stream) {
    const float* theta0 = (const float*)d_in[0];  // [B,N]
    const float* emb    = (const float*)d_in[1];  // [B,N,D]
    const float* omega  = (const float*)d_in[2];  // [N]
    float* out = (float*)d_out;                   // [B,N]

    // workspace layout (~42 MiB)
    unsigned short* En = (unsigned short*)d_ws;                    // B*N*D bf16
    unsigned char*  C  = (unsigned char*)(En + (size_t)B * N * D); // B*N*N fp8
    unsigned int*  msg = (unsigned int*)(C + (size_t)B * N * N);   // 2*B*N u32

    normalize_k<<<B * N / 4, 256, 0, stream>>>(emb, En);

    dim3 gC(N / 64, N / 64, B);
    build_c_k<<<gC, 256, 0, stream>>>(En, C);

    fused_steps_k<<<dim3(BPB, B), TPB, 0, stream>>>(C, theta0, out, omega, msg);
}